// Round 14
// baseline (110.669 us; speedup 1.0000x reference)
//
#include <hip/hip_runtime.h>
#include <hip/hip_bf16.h>

static constexpr int N = 100000;   // nodes
static constexpr int E = 1000000;  // edges
static constexpr int D = 64;       // feature dim
static constexpr int NB = 391;     // dst buckets of 256 nodes (391*256 >= N)
static constexpr int CAP = 3072;   // per-bucket edge capacity (mean 2560, ~+10 sigma)
static constexpr int PART_EPT = 8;
static constexpr int PART_CHUNK = 256 * PART_EPT;                        // 2048
static constexpr int PART_BLOCKS = (E + PART_CHUNK - 1) / PART_CHUNK;    // 489
static constexpr int LIN_BLOCKS = (N + 63) / 64;                         // 1563

typedef __attribute__((ext_vector_type(8))) short bf16x8;
typedef __attribute__((ext_vector_type(4))) float f32x4;

__device__ inline ushort f2bf(float f) {     // RNE f32 -> bf16 bits
    unsigned u = __float_as_uint(f);
    return (ushort)((u + 0x7fffu + ((u >> 16) & 1u)) >> 16);
}

// ---- init (98 blocks): zero cnt; block0: gcur, W->bf16, zero row, dis[N] --
__global__ __launch_bounds__(256) void k_init(const float* __restrict__ w,
                                              int* __restrict__ gcur,
                                              int* __restrict__ cnt,
                                              float* __restrict__ dis,
                                              ushort* __restrict__ wbf,
                                              ushort* __restrict__ hb) {
    int tid = threadIdx.x;
    int i = blockIdx.x * 1024 + tid * 4;         // zero cnt[N]
    if (i + 3 < N) {
        *reinterpret_cast<int4*>(cnt + i) = make_int4(0, 0, 0, 0);
    } else {
        for (int k = i; k < N; ++k) cnt[k] = 0;
    }
    if (blockIdx.x == 0) {
        int i0 = tid * 16;                       // W -> bf16 (4096 elems)
#pragma unroll
        for (int c = 0; c < 4; ++c) {
            float4 v = *reinterpret_cast<const float4*>(w + i0 + c * 4);
            ushort4 o;
            o.x = f2bf(v.x); o.y = f2bf(v.y); o.z = f2bf(v.z); o.w = f2bf(v.w);
            *reinterpret_cast<ushort4*>(wbf + i0 + c * 4) = o;
        }
        for (int b = tid; b < NB; b += 256) gcur[b] = 0;
        if (tid == 0) dis[N] = 0.f;
        if (tid < 32) reinterpret_cast<int*>(hb + N * D)[tid] = 0;  // zero row
    }
}

// ---- K1: bucket partition (blocks [0,PART_BLOCKS)) ∪ linear (rest) --------
// partition additionally maintains global per-node counts via fire-and-forget
// atomics (no return value -> no vmcnt wait on the hot path).
__global__ __launch_bounds__(256) void k_partlin(const int* __restrict__ ei,
                                                 const float* __restrict__ x,
                                                 const ushort* __restrict__ wbf,
                                                 int* __restrict__ gcur,
                                                 int* __restrict__ cnt,
                                                 int* __restrict__ part,
                                                 ushort* __restrict__ hb) {
    __shared__ int hcnt[NB];
    __shared__ int hcur[NB];
    int tid = threadIdx.x;
    if (blockIdx.x < PART_BLOCKS) {
        // ---------------- partition path ----------------
        for (int b = tid; b < NB; b += 256) hcnt[b] = 0;
        __syncthreads();
        int base = blockIdx.x * PART_CHUNK + tid;
        int ss[PART_EPT], tt[PART_EPT];
#pragma unroll
        for (int k = 0; k < PART_EPT; ++k) {      // phase A: local histogram
            int i = base + k * 256;
            int s = -1, t = 0;
            if (i < E) {
                s = ei[i];
                t = ei[E + i];
                if (s == t) s = -1;               // drop self loops
            }
            ss[k] = s; tt[k] = t;
            if (s >= 0) {
                atomicAdd(&hcnt[t >> 8], 1);
                atomicAdd(&cnt[t], 1);            // global node count (no-ret)
            }
        }
        __syncthreads();
        for (int b = tid; b < NB; b += 256) {     // phase B: reserve ranges
            int c = hcnt[b];
            hcur[b] = b * CAP + (c ? atomicAdd(&gcur[b], c) : 0);
        }
        __syncthreads();
#pragma unroll
        for (int k = 0; k < PART_EPT; ++k) {      // phase C: grouped scatter
            int s = ss[k];
            if (s >= 0) {
                int b = tt[k] >> 8;
                int pos = atomicAdd(&hcur[b], 1);
                if (pos < (b + 1) * CAP)          // safety, statistically never
                    part[pos] = s | ((tt[k] & 255) << 17);
            }
        }
    } else {
        // ---------------- MFMA linear path ----------------
        int lane = tid & 63, wave = tid >> 6;
        int tbase = (blockIdx.x - PART_BLOCKS) * 64 + wave * 16;
        if (tbase >= N) return;                   // wave-uniform
        int r15 = lane & 15, g4 = lane >> 4;
        int arow = tbase + r15;
        if (arow >= N) arow = N - 1;              // clamped load, store guarded
        bf16x8 afr[2];
#pragma unroll
        for (int ks = 0; ks < 2; ++ks) {
            const float* ap = x + arow * 64 + ks * 32 + g4 * 8;
            float4 v0 = *reinterpret_cast<const float4*>(ap);
            float4 v1 = *reinterpret_cast<const float4*>(ap + 4);
            bf16x8 a;
            a[0] = (short)f2bf(v0.x); a[1] = (short)f2bf(v0.y);
            a[2] = (short)f2bf(v0.z); a[3] = (short)f2bf(v0.w);
            a[4] = (short)f2bf(v1.x); a[5] = (short)f2bf(v1.y);
            a[6] = (short)f2bf(v1.z); a[7] = (short)f2bf(v1.w);
            afr[ks] = a;
        }
        f32x4 acc[4] = {};
#pragma unroll
        for (int nt = 0; nt < 4; ++nt)
#pragma unroll
            for (int ks = 0; ks < 2; ++ks) {
                bf16x8 b = *reinterpret_cast<const bf16x8*>(
                    wbf + (nt * 16 + r15) * 64 + ks * 32 + g4 * 8);
                acc[nt] = __builtin_amdgcn_mfma_f32_16x16x32_bf16(afr[ks], b, acc[nt], 0, 0, 0);
            }
#pragma unroll
        for (int r = 0; r < 4; ++r) {
            int node = tbase + g4 * 4 + r;
            if (node < N) {
#pragma unroll
                for (int nt = 0; nt < 4; ++nt)
                    hb[node * D + nt * 16 + r15] = f2bf(acc[nt][r]);
            }
        }
    }
}

// ---- per-bucket CSR: counts from cnt[] (coalesced), scan, scatter ---------
__global__ __launch_bounds__(512) void k_csr(const int* __restrict__ gcur,
                                             const int* __restrict__ part,
                                             const int* __restrict__ cnt,
                                             int2* __restrict__ rc,
                                             int* __restrict__ srcs,
                                             float* __restrict__ dis) {
    __shared__ int scanL[256];
    __shared__ int curL[256];
    int tid = threadIdx.x;
    int b = blockIdx.x;
    int node = b * 256 + tid;
    int c = 0;
    if (tid < 256) {
        c = (node < N) ? cnt[node] : 0;           // coalesced count load
        scanL[tid] = c;
    }
    __syncthreads();
    for (int off = 1; off < 256; off <<= 1) {     // inclusive scan over 256
        int v = 0;
        if (tid < 256 && tid >= off) v = scanL[tid - off];
        __syncthreads();
        if (tid < 256) scanL[tid] += v;
        __syncthreads();
    }
    if (tid < 256) {
        int excl = scanL[tid] - c;
        if (node < N) {
            rc[node] = make_int2(b * CAP + excl, c);
            dis[node] = rsqrtf((float)(c + 1));
        }
        curL[tid] = excl;
    }
    __syncthreads();
    int en = gcur[b];
    en = en < CAP ? en : CAP;
    const int* pb = part + b * CAP;
    for (int i = tid; i < en; i += 512) {
        int e = pb[i];
        int pos = atomicAdd(&curL[e >> 17], 1);
        srcs[b * CAP + pos] = e & 0x1FFFF;
    }
}

// ---- aggregate: one wave per node, 2-deep software-pipelined gather -------
// Octet q handles edge k0+q; lane loads 16B (8 bf16 dims). Two rounds'
// srcs/dis/row chains in flight; self-row/bias/dt hoisted before the loop.
#define FMACC8(d, v)                                                        \
    acc[0] = fmaf(d, __uint_as_float(((unsigned)(v).x) << 16), acc[0]);     \
    acc[1] = fmaf(d, __uint_as_float(((unsigned)(v).x) & 0xffff0000u), acc[1]); \
    acc[2] = fmaf(d, __uint_as_float(((unsigned)(v).y) << 16), acc[2]);     \
    acc[3] = fmaf(d, __uint_as_float(((unsigned)(v).y) & 0xffff0000u), acc[3]); \
    acc[4] = fmaf(d, __uint_as_float(((unsigned)(v).z) << 16), acc[4]);     \
    acc[5] = fmaf(d, __uint_as_float(((unsigned)(v).z) & 0xffff0000u), acc[5]); \
    acc[6] = fmaf(d, __uint_as_float(((unsigned)(v).w) << 16), acc[6]);     \
    acc[7] = fmaf(d, __uint_as_float(((unsigned)(v).w) & 0xffff0000u), acc[7]);

__global__ __launch_bounds__(256) void k_agg(const int2* __restrict__ rc,
                                             const int* __restrict__ srcs,
                                             const ushort* __restrict__ hb,
                                             const float* __restrict__ dis,
                                             const float* __restrict__ bias,
                                             float* __restrict__ out) {
    int g = blockIdx.x * 256 + threadIdx.x;
    int t = g >> 6, lane = g & 63;
    if (t >= N) return;
    int q = lane >> 3, l = lane & 7;
    int2 bc = rc[t];
    int base = bc.x, len = bc.y;

    // hoisted tail loads: self row, bias, dt (latency hides under the loop)
    int lb = lane & 7;
    int4 vt = *reinterpret_cast<const int4*>(hb + t * D + lb * 8);
    float4 ba = *reinterpret_cast<const float4*>(&bias[lb * 8]);
    float4 bb = *reinterpret_cast<const float4*>(&bias[lb * 8 + 4]);
    float dt = rsqrtf((float)(len + 1));

    float acc[8];
#pragma unroll
    for (int i = 0; i < 8; ++i) acc[i] = 0.f;

    // 2-deep pipeline: rounds 0 and 1 issued up front
    int s0 = (q < len) ? srcs[base + q] : N;              // N = zero row
    int s1 = (8 + q < len) ? srcs[base + 8 + q] : N;
    float d0 = dis[s0];
    int4  v0 = *reinterpret_cast<const int4*>(hb + s0 * D + l * 8);
    float d1 = dis[s1];
    int4  v1 = *reinterpret_cast<const int4*>(hb + s1 * D + l * 8);
    for (int k0 = 16; k0 < len; k0 += 8) {
        int idx = k0 + q;
        int s2 = (idx < len) ? srcs[base + idx] : N;
        float d2 = dis[s2];
        int4  v2 = *reinterpret_cast<const int4*>(hb + s2 * D + l * 8);
        FMACC8(d0, v0);
        d0 = d1; v0 = v1;
        d1 = d2; v1 = v2;
    }
    FMACC8(d0, v0);
    FMACC8(d1, v1);

#pragma unroll
    for (int i = 0; i < 8; ++i) {
        acc[i] += __shfl_down(acc[i], 32);
        acc[i] += __shfl_down(acc[i], 16);
        acc[i] += __shfl_down(acc[i], 8);
    }
    if (lane < 8) {                        // lanes 0..7 hold dims lane*8..+7
        FMACC8(dt, vt);                    // self message dt*h[t]
        float4 o0, o1;
        o0.x = fmaf(dt, acc[0], ba.x);
        o0.y = fmaf(dt, acc[1], ba.y);
        o0.z = fmaf(dt, acc[2], ba.z);
        o0.w = fmaf(dt, acc[3], ba.w);
        o1.x = fmaf(dt, acc[4], bb.x);
        o1.y = fmaf(dt, acc[5], bb.y);
        o1.z = fmaf(dt, acc[6], bb.z);
        o1.w = fmaf(dt, acc[7], bb.w);
        *reinterpret_cast<float4*>(out + t * D + lane * 8) = o0;
        *reinterpret_cast<float4*>(out + t * D + lane * 8 + 4) = o1;
    }
}

extern "C" void kernel_launch(void* const* d_in, const int* in_sizes, int n_in,
                              void* d_out, int out_size, void* d_ws, size_t ws_size,
                              hipStream_t stream) {
    const float* x    = (const float*)d_in[0];   // [N, 64]
    const int*   ei   = (const int*)d_in[1];     // [2, E]
    const float* w    = (const float*)d_in[2];   // [64, 64]
    const float* bias = (const float*)d_in[3];   // [64]
    float* out = (float*)d_out;                  // [N, 64]

    // workspace layout (16B aligned)
    char* ws = (char*)d_ws;
    int*    gcur = (int*)(ws);                   // NB ints          @ 0
    ushort* wbf  = (ushort*)(ws + 1664);         // 4096 bf16 (8 KB)
    int*    part = (int*)(ws + 9856);            // NB*CAP ints
    int*    srcs = (int*)(ws + 4814464);         // NB*CAP ints
    int*    cnt  = (int*)(ws + 9619072);         // N ints
    int2*   rc   = (int2*)(ws + 10019072);       // N int2 (800 KB)
    float*  dis  = (float*)(ws + 10819072);      // N+1 floats
    ushort* hb   = (ushort*)(ws + 11219200);     // (N+1)*64 bf16

    k_init   <<<98, 256, 0, stream>>>(w, gcur, cnt, dis, wbf, hb);
    k_partlin<<<PART_BLOCKS + LIN_BLOCKS, 256, 0, stream>>>(ei, x, wbf, gcur, cnt, part, hb);
    k_csr    <<<NB, 512, 0, stream>>>(gcur, part, cnt, rc, srcs, dis);
    k_agg    <<<(N * 64) / 256, 256, 0, stream>>>(rc, srcs, hb, dis, bias, out);
}

// Round 15
// 84.587 us; speedup vs baseline: 1.3083x; 1.3083x over previous
//
#include <hip/hip_runtime.h>
#include <hip/hip_bf16.h>

static constexpr int N = 100000;   // nodes
static constexpr int E = 1000000;  // edges
static constexpr int D = 64;       // feature dim
static constexpr int NB = 391;     // dst buckets of 256 nodes (391*256 >= N)
static constexpr int CAP = 3072;   // per-bucket edge capacity (mean 2560, ~+10 sigma)
static constexpr int PART_EPT = 8;
static constexpr int PART_CHUNK = 256 * PART_EPT;                        // 2048
static constexpr int PART_BLOCKS = (E + PART_CHUNK - 1) / PART_CHUNK;    // 489
static constexpr int LIN_BLOCKS = (N + 63) / 64;                         // 1563

typedef __attribute__((ext_vector_type(8))) short bf16x8;
typedef __attribute__((ext_vector_type(4))) float f32x4;

__device__ inline ushort f2bf(float f) {     // RNE f32 -> bf16 bits
    unsigned u = __float_as_uint(f);
    return (ushort)((u + 0x7fffu + ((u >> 16) & 1u)) >> 16);
}

// ---- init: zero gcur, W f32->bf16, zero dummy row N -----------------------
__global__ __launch_bounds__(256) void k_init(const float* __restrict__ w,
                                              int* __restrict__ gcur,
                                              ushort* __restrict__ wbf,
                                              ushort* __restrict__ hb) {
    int tid = threadIdx.x;
    int i0 = tid * 16;
#pragma unroll
    for (int c = 0; c < 4; ++c) {
        float4 v = *reinterpret_cast<const float4*>(w + i0 + c * 4);
        ushort4 o;
        o.x = f2bf(v.x); o.y = f2bf(v.y); o.z = f2bf(v.z); o.w = f2bf(v.w);
        *reinterpret_cast<ushort4*>(wbf + i0 + c * 4) = o;
    }
    for (int b = tid; b < NB; b += 256) gcur[b] = 0;
    if (tid < 32) reinterpret_cast<int*>(hb + N * D)[tid] = 0;   // zero row N
}

// ---- K1: bucket partition (blocks [0,PART_BLOCKS)) ∪ linear (rest) --------
__global__ __launch_bounds__(256) void k_partlin(const int* __restrict__ ei,
                                                 const float* __restrict__ x,
                                                 const ushort* __restrict__ wbf,
                                                 int* __restrict__ gcur,
                                                 int* __restrict__ part,
                                                 ushort* __restrict__ hb) {
    __shared__ int hcnt[NB];
    __shared__ int hcur[NB];
    int tid = threadIdx.x;
    if (blockIdx.x < PART_BLOCKS) {
        // ---------------- partition path ----------------
        for (int b = tid; b < NB; b += 256) hcnt[b] = 0;
        __syncthreads();
        int base = blockIdx.x * PART_CHUNK + tid;
        int ss[PART_EPT], tt[PART_EPT];
#pragma unroll
        for (int k = 0; k < PART_EPT; ++k) {      // phase A: local histogram
            int i = base + k * 256;
            int s = -1, t = 0;
            if (i < E) {
                s = ei[i];
                t = ei[E + i];
                if (s == t) s = -1;               // drop self loops
            }
            ss[k] = s; tt[k] = t;
            if (s >= 0) atomicAdd(&hcnt[t >> 8], 1);
        }
        __syncthreads();
        for (int b = tid; b < NB; b += 256) {     // phase B: reserve ranges
            int c = hcnt[b];
            hcur[b] = b * CAP + (c ? atomicAdd(&gcur[b], c) : 0);
        }
        __syncthreads();
#pragma unroll
        for (int k = 0; k < PART_EPT; ++k) {      // phase C: grouped scatter
            int s = ss[k];
            if (s >= 0) {
                int b = tt[k] >> 8;
                int pos = atomicAdd(&hcur[b], 1);
                if (pos < (b + 1) * CAP)          // safety, statistically never
                    part[pos] = s | ((tt[k] & 255) << 17);
            }
        }
    } else {
        // ---------------- MFMA linear path ----------------
        int lane = tid & 63, wave = tid >> 6;
        int tbase = (blockIdx.x - PART_BLOCKS) * 64 + wave * 16;
        if (tbase >= N) return;                   // wave-uniform
        int r15 = lane & 15, g4 = lane >> 4;
        int arow = tbase + r15;
        if (arow >= N) arow = N - 1;              // clamped load, store guarded
        bf16x8 afr[2];
#pragma unroll
        for (int ks = 0; ks < 2; ++ks) {
            const float* ap = x + arow * 64 + ks * 32 + g4 * 8;
            float4 v0 = *reinterpret_cast<const float4*>(ap);
            float4 v1 = *reinterpret_cast<const float4*>(ap + 4);
            bf16x8 a;
            a[0] = (short)f2bf(v0.x); a[1] = (short)f2bf(v0.y);
            a[2] = (short)f2bf(v0.z); a[3] = (short)f2bf(v0.w);
            a[4] = (short)f2bf(v1.x); a[5] = (short)f2bf(v1.y);
            a[6] = (short)f2bf(v1.z); a[7] = (short)f2bf(v1.w);
            afr[ks] = a;
        }
        f32x4 acc[4] = {};
#pragma unroll
        for (int nt = 0; nt < 4; ++nt)
#pragma unroll
            for (int ks = 0; ks < 2; ++ks) {
                bf16x8 b = *reinterpret_cast<const bf16x8*>(
                    wbf + (nt * 16 + r15) * 64 + ks * 32 + g4 * 8);
                acc[nt] = __builtin_amdgcn_mfma_f32_16x16x32_bf16(afr[ks], b, acc[nt], 0, 0, 0);
            }
#pragma unroll
        for (int r = 0; r < 4; ++r) {
            int node = tbase + g4 * 4 + r;
            if (node < N) {
#pragma unroll
                for (int nt = 0; nt < 4; ++nt)
                    hb[node * D + nt * 16 + r15] = f2bf(acc[nt][r]);
            }
        }
    }
}

// ---- per-bucket CSR build + hb row pre-scaling ----------------------------
// hist -> scan -> rc -> scatter -> scale hb rows by rsqrt(deg) so k_agg's
// inner loop needs no per-edge dis gather (2 VMEM/round instead of 3).
__global__ __launch_bounds__(512) void k_csr(const int* __restrict__ gcur,
                                             const int* __restrict__ part,
                                             int2* __restrict__ rc,
                                             int* __restrict__ srcs,
                                             ushort* __restrict__ hb) {
    __shared__ int cntL[256];
    __shared__ int scanL[256];
    __shared__ int curL[256];
    __shared__ float disF[256];
    int tid = threadIdx.x;
    int b = blockIdx.x;
    if (tid < 256) cntL[tid] = 0;
    __syncthreads();
    int en = gcur[b];
    en = en < CAP ? en : CAP;
    const int* pb = part + b * CAP;
    for (int i = tid; i < en; i += 512)
        atomicAdd(&cntL[pb[i] >> 17], 1);
    __syncthreads();
    if (tid < 256) scanL[tid] = cntL[tid];
    __syncthreads();
    for (int off = 1; off < 256; off <<= 1) {   // inclusive scan over 256
        int v = 0;
        if (tid < 256 && tid >= off) v = scanL[tid - off];
        __syncthreads();
        if (tid < 256) scanL[tid] += v;
        __syncthreads();
    }
    if (tid < 256) {
        int node = b * 256 + tid;
        int c = cntL[tid];
        int excl = scanL[tid] - c;
        if (node < N) rc[node] = make_int2(b * CAP + excl, c);
        curL[tid] = excl;
        disF[tid] = rsqrtf((float)(c + 1));
    }
    __syncthreads();
    for (int i = tid; i < en; i += 512) {
        int e = pb[i];
        int pos = atomicAdd(&curL[e >> 17], 1);
        srcs[b * CAP + pos] = e & 0x1FFFF;
    }
    __syncthreads();
    // ---- scale pass: hb[node,:] *= disF[node-local] (coalesced dwords) ----
    int nrows = N - b * 256;                    // rows in this bucket (<256 only for b=390)
    if (nrows > 256) nrows = 256;
    int ndw = nrows * 32;                       // 32 dwords per 64-bf16 row
    unsigned* hrow = reinterpret_cast<unsigned*>(hb) + (size_t)b * 256 * 32;
    for (int j = tid; j < ndw; j += 512) {
        unsigned u = hrow[j];
        float d = disF[j >> 5];
        float lo = __uint_as_float(u << 16) * d;
        float hi = __uint_as_float(u & 0xffff0000u) * d;
        hrow[j] = ((unsigned)f2bf(hi) << 16) | (unsigned)f2bf(lo);
    }
}

// ---- aggregate: one wave per node, 2-deep pipeline, pre-scaled rows -------
// Octet q handles edge k0+q; lane loads 16B (8 bf16 dims) of the PRE-SCALED
// row: inner loop = 2 VMEM per round (srcs + row), plain adds.
#define ACC8(v)                                                    \
    acc[0] += __uint_as_float(((unsigned)(v).x) << 16);            \
    acc[1] += __uint_as_float(((unsigned)(v).x) & 0xffff0000u);    \
    acc[2] += __uint_as_float(((unsigned)(v).y) << 16);            \
    acc[3] += __uint_as_float(((unsigned)(v).y) & 0xffff0000u);    \
    acc[4] += __uint_as_float(((unsigned)(v).z) << 16);            \
    acc[5] += __uint_as_float(((unsigned)(v).z) & 0xffff0000u);    \
    acc[6] += __uint_as_float(((unsigned)(v).w) << 16);            \
    acc[7] += __uint_as_float(((unsigned)(v).w) & 0xffff0000u);

__global__ __launch_bounds__(256) void k_agg(const int2* __restrict__ rc,
                                             const int* __restrict__ srcs,
                                             const ushort* __restrict__ hb,
                                             const float* __restrict__ bias,
                                             float* __restrict__ out) {
    int g = blockIdx.x * 256 + threadIdx.x;
    int t = g >> 6, lane = g & 63;
    if (t >= N) return;
    int q = lane >> 3, l = lane & 7;
    int2 bc = rc[t];
    int base = bc.x, len = bc.y;

    // hoisted tail loads: pre-scaled self row (= dt*h[t]), bias, dt
    int lb = lane & 7;
    int4 vt = *reinterpret_cast<const int4*>(hb + t * D + lb * 8);
    float4 ba = *reinterpret_cast<const float4*>(&bias[lb * 8]);
    float4 bb = *reinterpret_cast<const float4*>(&bias[lb * 8 + 4]);
    float dt = rsqrtf((float)(len + 1));

    float acc[8];
#pragma unroll
    for (int i = 0; i < 8; ++i) acc[i] = 0.f;

    // 2-deep pipeline: rounds 0 and 1 issued up front
    int s0 = (q < len) ? srcs[base + q] : N;              // N = zero row
    int s1 = (8 + q < len) ? srcs[base + 8 + q] : N;
    int4 v0 = *reinterpret_cast<const int4*>(hb + s0 * D + l * 8);
    int4 v1 = *reinterpret_cast<const int4*>(hb + s1 * D + l * 8);
    for (int k0 = 16; k0 < len; k0 += 8) {
        int idx = k0 + q;
        int s2 = (idx < len) ? srcs[base + idx] : N;
        int4 v2 = *reinterpret_cast<const int4*>(hb + s2 * D + l * 8);
        ACC8(v0);
        v0 = v1; v1 = v2;
    }
    ACC8(v0);
    ACC8(v1);

#pragma unroll
    for (int i = 0; i < 8; ++i) {
        acc[i] += __shfl_down(acc[i], 32);
        acc[i] += __shfl_down(acc[i], 16);
        acc[i] += __shfl_down(acc[i], 8);
    }
    if (lane < 8) {                        // lanes 0..7 hold dims lane*8..+7
        ACC8(vt);                          // self message (pre-scaled)
        float4 o0, o1;
        o0.x = fmaf(dt, acc[0], ba.x);
        o0.y = fmaf(dt, acc[1], ba.y);
        o0.z = fmaf(dt, acc[2], ba.z);
        o0.w = fmaf(dt, acc[3], ba.w);
        o1.x = fmaf(dt, acc[4], bb.x);
        o1.y = fmaf(dt, acc[5], bb.y);
        o1.z = fmaf(dt, acc[6], bb.z);
        o1.w = fmaf(dt, acc[7], bb.w);
        *reinterpret_cast<float4*>(out + t * D + lane * 8) = o0;
        *reinterpret_cast<float4*>(out + t * D + lane * 8 + 4) = o1;
    }
}

extern "C" void kernel_launch(void* const* d_in, const int* in_sizes, int n_in,
                              void* d_out, int out_size, void* d_ws, size_t ws_size,
                              hipStream_t stream) {
    const float* x    = (const float*)d_in[0];   // [N, 64]
    const int*   ei   = (const int*)d_in[1];     // [2, E]
    const float* w    = (const float*)d_in[2];   // [64, 64]
    const float* bias = (const float*)d_in[3];   // [64]
    float* out = (float*)d_out;                  // [N, 64]

    // workspace layout (16B aligned)
    char* ws = (char*)d_ws;
    int*    gcur = (int*)(ws);                   // NB ints          @ 0
    ushort* wbf  = (ushort*)(ws + 1664);         // 4096 bf16 (8 KB)
    int*    part = (int*)(ws + 9856);            // NB*CAP ints
    int*    srcs = (int*)(ws + 4814464);         // NB*CAP ints
    int2*   rc   = (int2*)(ws + 9619072);        // N int2 (800 KB)
    ushort* hb   = (ushort*)(ws + 10819200);     // (N+1)*64 bf16

    k_init   <<<1, 256, 0, stream>>>(w, gcur, wbf, hb);
    k_partlin<<<PART_BLOCKS + LIN_BLOCKS, 256, 0, stream>>>(ei, x, wbf, gcur, part, hb);
    k_csr    <<<NB, 512, 0, stream>>>(gcur, part, rc, srcs, hb);
    k_agg    <<<(N * 64) / 256, 256, 0, stream>>>(rc, srcs, hb, bias, out);
}

// Round 16
// 78.236 us; speedup vs baseline: 1.4146x; 1.0812x over previous
//
#include <hip/hip_runtime.h>
#include <hip/hip_bf16.h>

static constexpr int N = 100000;   // nodes
static constexpr int E = 1000000;  // edges
static constexpr int D = 64;       // feature dim
static constexpr int NB = 391;     // dst buckets of 256 nodes (391*256 >= N)
static constexpr int CAP = 3072;   // per-bucket edge capacity (mean 2560, ~+10 sigma)
static constexpr int PART_EPT = 8;
static constexpr int PART_CHUNK = 256 * PART_EPT;                        // 2048
static constexpr int PART_BLOCKS = (E + PART_CHUNK - 1) / PART_CHUNK;    // 489
static constexpr int LIN_BLOCKS = (N + 63) / 64;                         // 1563

typedef __attribute__((ext_vector_type(8))) short bf16x8;
typedef __attribute__((ext_vector_type(4))) float f32x4;

__device__ inline ushort f2bf(float f) {     // RNE f32 -> bf16 bits
    unsigned u = __float_as_uint(f);
    return (ushort)((u + 0x7fffu + ((u >> 16) & 1u)) >> 16);
}

// ---- init: zero gcur, W f32->bf16, dummy row N, dis[N] --------------------
__global__ __launch_bounds__(256) void k_init(const float* __restrict__ w,
                                              int* __restrict__ gcur,
                                              float* __restrict__ dis,
                                              ushort* __restrict__ wbf,
                                              ushort* __restrict__ hb) {
    int tid = threadIdx.x;
    int i0 = tid * 16;
#pragma unroll
    for (int c = 0; c < 4; ++c) {
        float4 v = *reinterpret_cast<const float4*>(w + i0 + c * 4);
        ushort4 o;
        o.x = f2bf(v.x); o.y = f2bf(v.y); o.z = f2bf(v.z); o.w = f2bf(v.w);
        *reinterpret_cast<ushort4*>(wbf + i0 + c * 4) = o;
    }
    for (int b = tid; b < NB; b += 256) gcur[b] = 0;
    if (tid == 0) dis[N] = 0.f;
    if (tid < 32) reinterpret_cast<int*>(hb + N * D)[tid] = 0;   // zero row N
}

// ---- K1: bucket partition (blocks [0,PART_BLOCKS)) ∪ linear (rest) --------
__global__ __launch_bounds__(256) void k_partlin(const int* __restrict__ ei,
                                                 const float* __restrict__ x,
                                                 const ushort* __restrict__ wbf,
                                                 int* __restrict__ gcur,
                                                 int* __restrict__ part,
                                                 ushort* __restrict__ hb) {
    __shared__ int hcnt[NB];
    __shared__ int hcur[NB];
    int tid = threadIdx.x;
    if (blockIdx.x < PART_BLOCKS) {
        // ---------------- partition path ----------------
        for (int b = tid; b < NB; b += 256) hcnt[b] = 0;
        __syncthreads();
        int base = blockIdx.x * PART_CHUNK + tid;
        int ss[PART_EPT], tt[PART_EPT];
#pragma unroll
        for (int k = 0; k < PART_EPT; ++k) {      // phase A: local histogram
            int i = base + k * 256;
            int s = -1, t = 0;
            if (i < E) {
                s = ei[i];
                t = ei[E + i];
                if (s == t) s = -1;               // drop self loops
            }
            ss[k] = s; tt[k] = t;
            if (s >= 0) atomicAdd(&hcnt[t >> 8], 1);
        }
        __syncthreads();
        for (int b = tid; b < NB; b += 256) {     // phase B: reserve ranges
            int c = hcnt[b];
            hcur[b] = b * CAP + (c ? atomicAdd(&gcur[b], c) : 0);
        }
        __syncthreads();
#pragma unroll
        for (int k = 0; k < PART_EPT; ++k) {      // phase C: grouped scatter
            int s = ss[k];
            if (s >= 0) {
                int b = tt[k] >> 8;
                int pos = atomicAdd(&hcur[b], 1);
                if (pos < (b + 1) * CAP)          // safety, statistically never
                    part[pos] = s | ((tt[k] & 255) << 17);
            }
        }
    } else {
        // ---------------- MFMA linear path ----------------
        int lane = tid & 63, wave = tid >> 6;
        int tbase = (blockIdx.x - PART_BLOCKS) * 64 + wave * 16;
        if (tbase >= N) return;                   // wave-uniform
        int r15 = lane & 15, g4 = lane >> 4;
        int arow = tbase + r15;
        if (arow >= N) arow = N - 1;              // clamped load, store guarded
        bf16x8 afr[2];
#pragma unroll
        for (int ks = 0; ks < 2; ++ks) {
            const float* ap = x + arow * 64 + ks * 32 + g4 * 8;
            float4 v0 = *reinterpret_cast<const float4*>(ap);
            float4 v1 = *reinterpret_cast<const float4*>(ap + 4);
            bf16x8 a;
            a[0] = (short)f2bf(v0.x); a[1] = (short)f2bf(v0.y);
            a[2] = (short)f2bf(v0.z); a[3] = (short)f2bf(v0.w);
            a[4] = (short)f2bf(v1.x); a[5] = (short)f2bf(v1.y);
            a[6] = (short)f2bf(v1.z); a[7] = (short)f2bf(v1.w);
            afr[ks] = a;
        }
        f32x4 acc[4] = {};
#pragma unroll
        for (int nt = 0; nt < 4; ++nt)
#pragma unroll
            for (int ks = 0; ks < 2; ++ks) {
                bf16x8 b = *reinterpret_cast<const bf16x8*>(
                    wbf + (nt * 16 + r15) * 64 + ks * 32 + g4 * 8);
                acc[nt] = __builtin_amdgcn_mfma_f32_16x16x32_bf16(afr[ks], b, acc[nt], 0, 0, 0);
            }
#pragma unroll
        for (int r = 0; r < 4; ++r) {
            int node = tbase + g4 * 4 + r;
            if (node < N) {
#pragma unroll
                for (int nt = 0; nt < 4; ++nt)
                    hb[node * D + nt * 16 + r15] = f2bf(acc[nt][r]);
            }
        }
    }
}

// ---- per-bucket CSR build in LDS; emits rc=(start,cnt) and dis ------------
__global__ __launch_bounds__(512) void k_csr(const int* __restrict__ gcur,
                                             const int* __restrict__ part,
                                             int2* __restrict__ rc,
                                             int* __restrict__ srcs,
                                             float* __restrict__ dis) {
    __shared__ int cntL[256];
    __shared__ int scanL[256];
    __shared__ int curL[256];
    int tid = threadIdx.x;
    int b = blockIdx.x;
    if (tid < 256) cntL[tid] = 0;
    __syncthreads();
    int en = gcur[b];
    en = en < CAP ? en : CAP;
    const int* pb = part + b * CAP;
    for (int i = tid; i < en; i += 512)
        atomicAdd(&cntL[pb[i] >> 17], 1);
    __syncthreads();
    if (tid < 256) scanL[tid] = cntL[tid];
    __syncthreads();
    for (int off = 1; off < 256; off <<= 1) {   // inclusive scan over 256
        int v = 0;
        if (tid < 256 && tid >= off) v = scanL[tid - off];
        __syncthreads();
        if (tid < 256) scanL[tid] += v;
        __syncthreads();
    }
    if (tid < 256) {
        int node = b * 256 + tid;
        int excl = scanL[tid] - cntL[tid];
        if (node < N) {
            rc[node] = make_int2(b * CAP + excl, cntL[tid]);
            dis[node] = rsqrtf((float)(cntL[tid] + 1));
        }
        curL[tid] = excl;
    }
    __syncthreads();
    for (int i = tid; i < en; i += 512) {
        int e = pb[i];
        int pos = atomicAdd(&curL[e >> 17], 1);
        srcs[b * CAP + pos] = e & 0x1FFFF;
    }
}

// ---- aggregate: one wave per node, 2-deep software-pipelined gather -------
// Octet q handles edge k0+q; lane loads 16B (8 bf16 dims). Two rounds'
// srcs/dis/row chains in flight; self-row/bias/dt hoisted before the loop.
#define FMACC8(d, v)                                                        \
    acc[0] = fmaf(d, __uint_as_float(((unsigned)(v).x) << 16), acc[0]);     \
    acc[1] = fmaf(d, __uint_as_float(((unsigned)(v).x) & 0xffff0000u), acc[1]); \
    acc[2] = fmaf(d, __uint_as_float(((unsigned)(v).y) << 16), acc[2]);     \
    acc[3] = fmaf(d, __uint_as_float(((unsigned)(v).y) & 0xffff0000u), acc[3]); \
    acc[4] = fmaf(d, __uint_as_float(((unsigned)(v).z) << 16), acc[4]);     \
    acc[5] = fmaf(d, __uint_as_float(((unsigned)(v).z) & 0xffff0000u), acc[5]); \
    acc[6] = fmaf(d, __uint_as_float(((unsigned)(v).w) << 16), acc[6]);     \
    acc[7] = fmaf(d, __uint_as_float(((unsigned)(v).w) & 0xffff0000u), acc[7]);

__global__ __launch_bounds__(256) void k_agg(const int2* __restrict__ rc,
                                             const int* __restrict__ srcs,
                                             const ushort* __restrict__ hb,
                                             const float* __restrict__ dis,
                                             const float* __restrict__ bias,
                                             float* __restrict__ out) {
    int g = blockIdx.x * 256 + threadIdx.x;
    int t = g >> 6, lane = g & 63;
    if (t >= N) return;
    int q = lane >> 3, l = lane & 7;
    int2 bc = rc[t];
    int base = bc.x, len = bc.y;

    // hoisted tail loads: self row, bias, dt (latency hides under the loop)
    int lb = lane & 7;
    int4 vt = *reinterpret_cast<const int4*>(hb + t * D + lb * 8);
    float4 ba = *reinterpret_cast<const float4*>(&bias[lb * 8]);
    float4 bb = *reinterpret_cast<const float4*>(&bias[lb * 8 + 4]);
    float dt = rsqrtf((float)(len + 1));

    float acc[8];
#pragma unroll
    for (int i = 0; i < 8; ++i) acc[i] = 0.f;

    // 2-deep pipeline: rounds 0 and 1 issued up front
    int s0 = (q < len) ? srcs[base + q] : N;              // N = zero row
    int s1 = (8 + q < len) ? srcs[base + 8 + q] : N;
    float d0 = dis[s0];
    int4  v0 = *reinterpret_cast<const int4*>(hb + s0 * D + l * 8);
    float d1 = dis[s1];
    int4  v1 = *reinterpret_cast<const int4*>(hb + s1 * D + l * 8);
    for (int k0 = 16; k0 < len; k0 += 8) {
        int idx = k0 + q;
        int s2 = (idx < len) ? srcs[base + idx] : N;
        float d2 = dis[s2];
        int4  v2 = *reinterpret_cast<const int4*>(hb + s2 * D + l * 8);
        FMACC8(d0, v0);
        d0 = d1; v0 = v1;
        d1 = d2; v1 = v2;
    }
    FMACC8(d0, v0);
    FMACC8(d1, v1);

#pragma unroll
    for (int i = 0; i < 8; ++i) {
        acc[i] += __shfl_down(acc[i], 32);
        acc[i] += __shfl_down(acc[i], 16);
        acc[i] += __shfl_down(acc[i], 8);
    }
    if (lane < 8) {                        // lanes 0..7 hold dims lane*8..+7
        FMACC8(dt, vt);                    // self message dt*h[t]
        float4 o0, o1;
        o0.x = fmaf(dt, acc[0], ba.x);
        o0.y = fmaf(dt, acc[1], ba.y);
        o0.z = fmaf(dt, acc[2], ba.z);
        o0.w = fmaf(dt, acc[3], ba.w);
        o1.x = fmaf(dt, acc[4], bb.x);
        o1.y = fmaf(dt, acc[5], bb.y);
        o1.z = fmaf(dt, acc[6], bb.z);
        o1.w = fmaf(dt, acc[7], bb.w);
        *reinterpret_cast<float4*>(out + t * D + lane * 8) = o0;
        *reinterpret_cast<float4*>(out + t * D + lane * 8 + 4) = o1;
    }
}

extern "C" void kernel_launch(void* const* d_in, const int* in_sizes, int n_in,
                              void* d_out, int out_size, void* d_ws, size_t ws_size,
                              hipStream_t stream) {
    const float* x    = (const float*)d_in[0];   // [N, 64]
    const int*   ei   = (const int*)d_in[1];     // [2, E]
    const float* w    = (const float*)d_in[2];   // [64, 64]
    const float* bias = (const float*)d_in[3];   // [64]
    float* out = (float*)d_out;                  // [N, 64]

    // workspace layout (16B aligned)
    char* ws = (char*)d_ws;
    int*    gcur = (int*)(ws);                   // NB ints          @ 0
    ushort* wbf  = (ushort*)(ws + 1664);         // 4096 bf16 (8 KB)
    int*    part = (int*)(ws + 9856);            // NB*CAP ints
    int*    srcs = (int*)(ws + 4814464);         // NB*CAP ints
    int2*   rc   = (int2*)(ws + 9619072);        // N int2 (800 KB)
    float*  dis  = (float*)(ws + 10419072);      // N+1 floats
    ushort* hb   = (ushort*)(ws + 10819200);     // (N+1)*64 bf16

    k_init   <<<1, 256, 0, stream>>>(w, gcur, dis, wbf, hb);
    k_partlin<<<PART_BLOCKS + LIN_BLOCKS, 256, 0, stream>>>(ei, x, wbf, gcur, part, hb);
    k_csr    <<<NB, 512, 0, stream>>>(gcur, part, rc, srcs, dis);
    k_agg    <<<(N * 64) / 256, 256, 0, stream>>>(rc, srcs, hb, dis, bias, out);
}